// Round 13
// baseline (44.476 us; speedup 1.0000x reference)
//
#include <hip/hip_runtime.h>
#include <stdint.h>

#define BATCH 128
#define MAXN 1024
#define NF 9
#define DIM 256
#define NCLS 10

// Combined-table sections (rows of 256):
#define BASE1 119
#define BASE2 179
#define BASE3 299
#define QROWS 443

#define TBLK 114                      // table-prep blocks (3 cls + 111 Q)
#define PACKBLK (BATCH * MAXN / 256)  // 512 index-pack blocks

typedef __attribute__((ext_vector_type(4))) float f32x4;
typedef __attribute__((ext_vector_type(2))) uint32_t u32x2;

__device__ __forceinline__ ushort f32_to_bf16_rne(float x) {
  uint32_t u = __float_as_uint(x);
  u += 0x7fffu + ((u >> 16) & 1u);
  return (ushort)(u >> 16);
}

__device__ __forceinline__ f32x4 bf4_to_f32x4(u32x2 v) {
  f32x4 r;
  r.x = __uint_as_float(v.x << 16);
  r.y = __uint_as_float(v.x & 0xffff0000u);
  r.z = __uint_as_float(v.y << 16);
  r.w = __uint_as_float(v.y & 0xffff0000u);
  return r;
}

// ---------------------------------------------------------------------------
// Prep (unchanged, proven ~3us): 114 table blocks + 512 index-pack blocks.
//  bid in [0,3):     clsT[c][o] f32 = lin_b[o] + W2[o]·rxn_emb[c]
//  bid in [3,114):   Qb[q][o] bf16 = W1[o]·S_q  (row-major 443x256)
//  bid in [114,626): jpack[node] = int4 of the 4 combined-table rows
// ---------------------------------------------------------------------------
__global__ __launch_bounds__(256) void prep_kernel(
    const float* __restrict__ rxn_emb, const float* __restrict__ lin_w,
    const float* __restrict__ lin_b, const float* __restrict__ atom_emb,
    const int* __restrict__ node_feat,
    ushort* __restrict__ Qb, float* __restrict__ clsT, int4* __restrict__ jpack)
{
  const int bid = blockIdx.x;
  const int t = threadIdx.x;

  if (bid >= TBLK) {  // ---- index-pack path ----
    const int node = (bid - TBLK) * 256 + t;
    const int* p = node_feat + (size_t)node * NF;
    int4 jv;
    jv.x = p[0];
    jv.y = BASE1 + p[1] * 12 + p[2];
    jv.z = BASE2 + p[3] * 10 + p[4];
    jv.w = BASE3 + ((p[5] * 6 + p[6]) * 2 + p[7]) * 2 + p[8];
    jpack[node] = jv;
    return;
  }

  // ---- table path: 4 rows/block, one W sweep amortized ----
  __shared__ float S[4][DIM];
  const bool isCls = bid < 3;
  const int row0 = isCls ? bid * 4 : (bid - 3) * 4;
  const int rmax = isCls ? NCLS : QROWS;
  const int nrows = (rmax - row0 < 4) ? (rmax - row0) : 4;

#pragma unroll
  for (int r = 0; r < 4; ++r) {
    float v = 0.f;
    if (r < nrows) {
      const int q = row0 + r;
      if (isCls) {
        v = rxn_emb[q * DIM + t];
      } else if (q < BASE1) {
        v = atom_emb[q * DIM + t];
      } else if (q < BASE2) {
        int x = q - BASE1;
        v = atom_emb[(119 + x / 12) * DIM + t] + atom_emb[(124 + x % 12) * DIM + t];
      } else if (q < BASE3) {
        int x = q - BASE2;
        v = atom_emb[(136 + x / 10) * DIM + t] + atom_emb[(148 + x % 10) * DIM + t];
      } else {
        int x = q - BASE3;
        int i8 = x & 1, i7 = (x >> 1) & 1, y = x >> 2;
        v = atom_emb[(158 + y / 6) * DIM + t] + atom_emb[(164 + y % 6) * DIM + t]
          + atom_emb[(170 + i7) * DIM + t] + atom_emb[(172 + i8) * DIM + t];
      }
    }
    S[r][t] = v;
  }
  __syncthreads();

  const float* wrow = lin_w + (size_t)t * 2 * DIM + (isCls ? DIM : 0);
  const float init = isCls ? lin_b[t] : 0.f;
  float a0 = init, a1 = init, a2 = init, a3 = init;
#pragma unroll 4
  for (int d = 0; d < DIM; d += 4) {
    float4 w4 = *(const float4*)(wrow + d);
    a0 += w4.x * S[0][d] + w4.y * S[0][d + 1] + w4.z * S[0][d + 2] + w4.w * S[0][d + 3];
    a1 += w4.x * S[1][d] + w4.y * S[1][d + 1] + w4.z * S[1][d + 2] + w4.w * S[1][d + 3];
    a2 += w4.x * S[2][d] + w4.y * S[2][d + 1] + w4.z * S[2][d + 2] + w4.w * S[2][d + 3];
    a3 += w4.x * S[3][d] + w4.y * S[3][d + 1] + w4.z * S[3][d + 2] + w4.w * S[3][d + 3];
  }
  if (isCls) {
    if (0 < nrows) clsT[(row0 + 0) * DIM + t] = a0;
    if (1 < nrows) clsT[(row0 + 1) * DIM + t] = a1;
    if (2 < nrows) clsT[(row0 + 2) * DIM + t] = a2;
    if (3 < nrows) clsT[(row0 + 3) * DIM + t] = a3;
  } else {
    if (0 < nrows) Qb[(row0 + 0) * DIM + t] = f32_to_bf16_rne(a0);
    if (1 < nrows) Qb[(row0 + 1) * DIM + t] = f32_to_bf16_rne(a1);
    if (2 < nrows) Qb[(row0 + 2) * DIM + t] = f32_to_bf16_rne(a2);
    if (3 < nrows) Qb[(row0 + 3) * DIM + t] = f32_to_bf16_rne(a3);
  }
}

// ---------------------------------------------------------------------------
// Main: 1024 blocks x 256 threads — LONG-LIVED WAVES (4096 waves, 16/CU, one
// resident generation), each wave owns 32 nodes = 8 strips x 4 nodes,
// SOFTWARE-PIPELINED 1-ahead: issue strip s+1's 16 gathers, then compute +
// store strip s. vmcnt ordering makes the strip-(s+1) wait counted (stores
// issued after those loads are never drained by it). Per-wave store issue is
// periodic (every strip) instead of one terminal burst; waves decorrelate ->
// continuous CU-level store stream (the fill kernels' property — they hit
// 6.7 TB/s at 10% occupancy with zero load phases; our short-lived waves all
// load together / store together at ~50% store-pipe duty = the 3.4 TB/s
// plateau common to rounds 4-12).
// ---------------------------------------------------------------------------
__global__ __launch_bounds__(256, 4) void main_kernel(
    const int4* __restrict__ jpack, const int* __restrict__ num_nodes,
    const int* __restrict__ rxn_class,
    const ushort* __restrict__ Qb, const float* __restrict__ clsT,
    float* __restrict__ out)
{
  const int tid = threadIdx.x;
  const int lane = tid & 63;
  const int w = __builtin_amdgcn_readfirstlane(tid >> 6);
  const int wid = blockIdx.x * 4 + w;   // 0..4095
  const int b = wid >> 5;               // 32 waves per batch
  const int n0w = (wid & 31) << 5;      // 32 nodes per wave
  const int nn = num_nodes[b];

  const f32x4 cf = ((const f32x4*)clsT)[rxn_class[b] * 64 + lane];
  f32x4* __restrict__ outp = (f32x4*)out + ((size_t)(b * MAXN + n0w)) * 64 + lane;

  if (n0w >= nn) {  // fully masked window: 32 back-to-back 1KB stores
#pragma unroll
    for (int i = 0; i < 32; ++i)
      outp[i * 64] = cf;
    return;
  }

  const int4* __restrict__ jp = jpack + (size_t)b * MAXN + n0w;
  const u32x2* __restrict__ Q2 = (const u32x2*)Qb;

  if (n0w + 32 <= nn) {  // fully valid window — 8-strip pipeline, 1-ahead
    u32x2 g[2][16];      // [parity][node*4 + table]; static after full unroll

    // prologue: strip 0 gathers
#pragma unroll
    for (int i = 0; i < 4; ++i) {
      const int4 jv = jp[i];
      g[0][i * 4 + 0] = Q2[jv.x * 64 + lane];
      g[0][i * 4 + 1] = Q2[jv.y * 64 + lane];
      g[0][i * 4 + 2] = Q2[jv.z * 64 + lane];
      g[0][i * 4 + 3] = Q2[jv.w * 64 + lane];
    }

#pragma unroll
    for (int s = 0; s < 8; ++s) {
      const int cur = s & 1, nxt = cur ^ 1;
      if (s < 7) {  // issue next strip's gathers BEFORE consuming current
#pragma unroll
        for (int i = 0; i < 4; ++i) {
          const int4 jv = jp[(s + 1) * 4 + i];
          g[nxt][i * 4 + 0] = Q2[jv.x * 64 + lane];
          g[nxt][i * 4 + 1] = Q2[jv.y * 64 + lane];
          g[nxt][i * 4 + 2] = Q2[jv.z * 64 + lane];
          g[nxt][i * 4 + 3] = Q2[jv.w * 64 + lane];
        }
      }
#pragma unroll
      for (int i = 0; i < 4; ++i) {
        const f32x4 r = cf +
            ((bf4_to_f32x4(g[cur][i * 4 + 0]) + bf4_to_f32x4(g[cur][i * 4 + 1])) +
             (bf4_to_f32x4(g[cur][i * 4 + 2]) + bf4_to_f32x4(g[cur][i * 4 + 3])));
        outp[(s * 4 + i) * 64] = r;
      }
    }
    return;
  }

  // partial window (<=1 per batch): branchless float-mask, simple loop
#pragma unroll 4
  for (int i = 0; i < 32; ++i) {
    const int4 jv = jp[i];
    const u32x2 v0 = Q2[jv.x * 64 + lane];
    const u32x2 v1 = Q2[jv.y * 64 + lane];
    const u32x2 v2 = Q2[jv.z * 64 + lane];
    const u32x2 v3 = Q2[jv.w * 64 + lane];
    const float m = (n0w + i < nn) ? 1.f : 0.f;
    const f32x4 s = (bf4_to_f32x4(v0) + bf4_to_f32x4(v1))
                  + (bf4_to_f32x4(v2) + bf4_to_f32x4(v3));
    outp[i * 64] = cf + m * s;
  }
}

extern "C" void kernel_launch(void* const* d_in, const int* in_sizes, int n_in,
                              void* d_out, int out_size, void* d_ws, size_t ws_size,
                              hipStream_t stream) {
  const int* node_feat = (const int*)d_in[0];
  const int* num_nodes = (const int*)d_in[1];
  const int* rxn_class = (const int*)d_in[2];
  const float* atom_emb = (const float*)d_in[3];
  const float* rxn_emb = (const float*)d_in[4];
  const float* lin_w = (const float*)d_in[5];
  const float* lin_b = (const float*)d_in[6];
  float* outp = (float*)d_out;

  // workspace: Qb row-major bf16 (226816 B) | clsT (10240 B) | jpack @256KB
  ushort* Qb = (ushort*)d_ws;
  float* clsT = (float*)((char*)d_ws + QROWS * DIM * sizeof(ushort));
  int4* jpack = (int4*)((char*)d_ws + 262144);

  prep_kernel<<<TBLK + PACKBLK, 256, 0, stream>>>(rxn_emb, lin_w, lin_b,
                                                  atom_emb, node_feat,
                                                  Qb, clsT, jpack);
  main_kernel<<<1024, 256, 0, stream>>>(jpack, num_nodes, rxn_class,
                                        Qb, clsT, outp);
}